// Round 1
// baseline (224.815 us; speedup 1.0000x reference)
//
#include <hip/hip_runtime.h>

#define WAVE 64

// idx may be int32 (JAX default, x64 disabled) or int64 (x64 enabled).
// Device-side detection: sample odd 32-bit words in the upper half of the
// first N words. int64 layout -> those are high words of elements < 2^31
// (values in [0,S)) -> all zero. int32 layout (sorted, median ~S/2) -> nonzero.
__global__ void detect_idx64(const unsigned int* __restrict__ w32, long long N,
                             int* __restrict__ flag) {
    if (blockIdx.x == 0 && threadIdx.x == 0) {
        long long base = (N / 2) | 1LL;                 // odd position
        long long stride = ((N / 2) / 64) & ~1LL;       // even stride keeps parity
        if (stride < 2) stride = 2;
        int nonzero = 0;
        for (int k = 0; k < 64; ++k) {
            long long p = base + (long long)k * stride;
            if (p >= N) break;
            nonzero |= (w32[p] != 0u) ? 1 : 0;
        }
        *flag = nonzero ? 0 : 1;   // 1 -> int64
    }
}

__device__ __forceinline__ long long load_idx(const void* __restrict__ p,
                                              long long i, int is64) {
    return is64 ? ((const long long*)p)[i] : (long long)((const int*)p)[i];
}

// One block per segment. idx sorted -> binary search [lo,hi), block-reduce.
// seg[s] = (cx, cy, cz, 1/(diam+0.01));  diam_out[s] = diam (goes to d_out tail).
__global__ void seg_stats(const float* __restrict__ pos,
                          const float* __restrict__ w,
                          const void* __restrict__ idxp,
                          const int* __restrict__ flag,
                          float4* __restrict__ seg,
                          float* __restrict__ diam_out,
                          long long N) {
    const int s = blockIdx.x;
    const int is64 = *flag;

    __shared__ long long srange[2];
    if (threadIdx.x < 2) {
        long long target = (long long)s + threadIdx.x;  // lower_bound(s), lower_bound(s+1)
        long long lo = 0, hi = N;
        while (lo < hi) {
            long long mid = (lo + hi) >> 1;
            if (load_idx(idxp, mid, is64) < target) lo = mid + 1; else hi = mid;
        }
        srange[threadIdx.x] = lo;
    }
    __syncthreads();
    const long long lo = srange[0], hi = srange[1];

    float mnx = INFINITY,  mny = INFINITY,  mnz = INFINITY;
    float mxx = -INFINITY, mxy = -INFINITY, mxz = -INFINITY;
    float sw = 0.f, swx = 0.f, swy = 0.f, swz = 0.f;

    for (long long i = lo + threadIdx.x; i < hi; i += blockDim.x) {
        float x = pos[3*i], y = pos[3*i+1], z = pos[3*i+2];
        float ww = w[i];
        mnx = fminf(mnx, x); mxx = fmaxf(mxx, x);
        mny = fminf(mny, y); mxy = fmaxf(mxy, y);
        mnz = fminf(mnz, z); mxz = fmaxf(mxz, z);
        sw += ww;
        swx = fmaf(ww, x, swx);
        swy = fmaf(ww, y, swy);
        swz = fmaf(ww, z, swz);
    }

    // wave reduction (width 64)
    #pragma unroll
    for (int off = WAVE / 2; off > 0; off >>= 1) {
        mnx = fminf(mnx, __shfl_down(mnx, off));
        mny = fminf(mny, __shfl_down(mny, off));
        mnz = fminf(mnz, __shfl_down(mnz, off));
        mxx = fmaxf(mxx, __shfl_down(mxx, off));
        mxy = fmaxf(mxy, __shfl_down(mxy, off));
        mxz = fmaxf(mxz, __shfl_down(mxz, off));
        sw  += __shfl_down(sw,  off);
        swx += __shfl_down(swx, off);
        swy += __shfl_down(swy, off);
        swz += __shfl_down(swz, off);
    }

    __shared__ float sm[4][10];
    const int wid = threadIdx.x / WAVE, lane = threadIdx.x % WAVE;
    if (lane == 0) {
        sm[wid][0] = mnx; sm[wid][1] = mny; sm[wid][2] = mnz;
        sm[wid][3] = mxx; sm[wid][4] = mxy; sm[wid][5] = mxz;
        sm[wid][6] = sw;  sm[wid][7] = swx; sm[wid][8] = swy; sm[wid][9] = swz;
    }
    __syncthreads();
    if (threadIdx.x == 0) {
        const int nw = blockDim.x / WAVE;
        for (int k = 1; k < nw; ++k) {
            mnx = fminf(mnx, sm[k][0]); mny = fminf(mny, sm[k][1]); mnz = fminf(mnz, sm[k][2]);
            mxx = fmaxf(mxx, sm[k][3]); mxy = fmaxf(mxy, sm[k][4]); mxz = fmaxf(mxz, sm[k][5]);
            sw += sm[k][6]; swx += sm[k][7]; swy += sm[k][8]; swz += sm[k][9];
        }
        float diam = fmaxf(mxx - mnx, fmaxf(mxy - mny, mxz - mnz));
        float wsafe = (sw == 0.f) ? 1.f : sw;
        seg[s] = make_float4(swx / wsafe, swy / wsafe, swz / wsafe,
                             1.f / (diam + 0.01f));
        diam_out[s] = diam;
    }
}

// Elementwise: out = (pos - center[idx]) * inv(diam[idx]+0.01). 4 points/thread,
// 3x float4 in / 3x float4 out.
__global__ void normalize_pts(const float* __restrict__ pos,
                              const void* __restrict__ idxp,
                              const int* __restrict__ flag,
                              const float4* __restrict__ seg,
                              float* __restrict__ out,
                              long long N) {
    long long t = (long long)blockIdx.x * blockDim.x + threadIdx.x;
    if (t >= (N >> 2)) return;
    const int is64 = *flag;

    const float4* __restrict__ pin = (const float4*)pos;
    float4 p0 = pin[t*3+0], p1 = pin[t*3+1], p2 = pin[t*3+2];
    const long long b = t << 2;

    float4 r0, r1, r2;
    {
        float4 sg = seg[load_idx(idxp, b + 0, is64)];
        r0.x = (p0.x - sg.x) * sg.w;
        r0.y = (p0.y - sg.y) * sg.w;
        r0.z = (p0.z - sg.z) * sg.w;
    }
    {
        float4 sg = seg[load_idx(idxp, b + 1, is64)];
        r0.w = (p0.w - sg.x) * sg.w;
        r1.x = (p1.x - sg.y) * sg.w;
        r1.y = (p1.y - sg.z) * sg.w;
    }
    {
        float4 sg = seg[load_idx(idxp, b + 2, is64)];
        r1.z = (p1.z - sg.x) * sg.w;
        r1.w = (p1.w - sg.y) * sg.w;
        r2.x = (p2.x - sg.z) * sg.w;
    }
    {
        float4 sg = seg[load_idx(idxp, b + 3, is64)];
        r2.y = (p2.y - sg.x) * sg.w;
        r2.z = (p2.z - sg.y) * sg.w;
        r2.w = (p2.w - sg.z) * sg.w;
    }
    float4* __restrict__ pout = (float4*)out;
    pout[t*3+0] = r0; pout[t*3+1] = r1; pout[t*3+2] = r2;
}

extern "C" void kernel_launch(void* const* d_in, const int* in_sizes, int n_in,
                              void* d_out, int out_size, void* d_ws, size_t ws_size,
                              hipStream_t stream) {
    const float* pos  = (const float*)d_in[0];
    const void*  idxp = d_in[1];
    const float* w    = (const float*)d_in[2];

    const long long N = (long long)in_sizes[0] / 3;     // 8388608
    const int S = out_size - in_sizes[0];               // 32768

    float* out = (float*)d_out;
    float* diam_out = out + (long long)in_sizes[0];     // tail of d_out

    int*    flag = (int*)d_ws;
    float4* seg  = (float4*)((char*)d_ws + 256);        // S * 16 B = 512 KB

    detect_idx64<<<1, 64, 0, stream>>>((const unsigned int*)idxp, N, flag);
    seg_stats<<<S, 256, 0, stream>>>(pos, w, idxp, flag, seg, diam_out, N);

    const long long nt = N >> 2;                        // 4 points per thread
    const int blocks = (int)((nt + 255) / 256);
    normalize_pts<<<blocks, 256, 0, stream>>>(pos, idxp, flag, seg, out, N);
}

// Round 2
// 92.135 us; speedup vs baseline: 2.4401x; 2.4401x over previous
//
#include <hip/hip_runtime.h>

#define WAVE 64

// idx may be int32 (JAX default) or int64 (x64 enabled). Detection: odd 32-bit
// words in the upper half are high words of values < 2^31 under int64 layout
// (all zero); under int32 layout they are sorted values ~S/2 (nonzero).
__global__ void detect_idx64(const unsigned int* __restrict__ w32, long long N,
                             int* __restrict__ flag) {
    long long base = (N / 2) | 1LL;                 // odd position
    long long stride = ((N / 2) / 64) & ~1LL;       // even stride keeps parity
    if (stride < 2) stride = 2;
    long long p = base + (long long)threadIdx.x * stride;
    unsigned int v = (p < N) ? w32[p] : 0u;
    unsigned long long nz = __ballot(v != 0u);
    if (threadIdx.x == 0) *flag = (nz == 0ULL) ? 1 : 0;   // 1 -> int64
}

__device__ __forceinline__ int load_idx(const void* __restrict__ p,
                                        long long i, int is64) {
    return is64 ? (int)((const long long*)p)[i] : ((const int*)p)[i];
}

// Coalesced pass over idx: start[s] = lower_bound(idx, s). idx sorted, so
// wherever the value changes (prev < cur) write start[prev+1 .. cur] = i.
// Thread N-1 backfills the tail. Total writes = S+1.
__global__ void find_bounds(const void* __restrict__ idxp,
                            const int* __restrict__ flag,
                            int* __restrict__ start,
                            long long N, int S) {
    long long i = (long long)blockIdx.x * blockDim.x + threadIdx.x;
    if (i >= N) return;
    const int is64 = *flag;
    int cur  = load_idx(idxp, i, is64);
    int prev = (i == 0) ? -1 : load_idx(idxp, i - 1, is64);
    for (int s = prev + 1; s <= cur; ++s) start[s] = (int)i;
    if (i == N - 1)
        for (int s = cur + 1; s <= S; ++s) start[s] = (int)N;
}

// One WAVE per segment, 4 segments per 256-thread block. No LDS, no barrier.
// seg[s] = (cx, cy, cz, 1/(diam+0.01));  diam_out[s] = diam.
__global__ void seg_stats(const float* __restrict__ pos,
                          const float* __restrict__ w,
                          const int* __restrict__ start,
                          float4* __restrict__ seg,
                          float* __restrict__ diam_out,
                          int S) {
    const int wid  = threadIdx.x >> 6;
    const int lane = threadIdx.x & 63;
    const int s = blockIdx.x * 4 + wid;
    if (s >= S) return;

    const int lo = start[s], hi = start[s + 1];

    float mnx = INFINITY,  mny = INFINITY,  mnz = INFINITY;
    float mxx = -INFINITY, mxy = -INFINITY, mxz = -INFINITY;
    float sw = 0.f, swx = 0.f, swy = 0.f, swz = 0.f;

    for (int i = lo + lane; i < hi; i += WAVE) {
        float x = pos[3LL*i], y = pos[3LL*i+1], z = pos[3LL*i+2];
        float ww = w[i];
        mnx = fminf(mnx, x); mxx = fmaxf(mxx, x);
        mny = fminf(mny, y); mxy = fmaxf(mxy, y);
        mnz = fminf(mnz, z); mxz = fmaxf(mxz, z);
        sw += ww;
        swx = fmaf(ww, x, swx);
        swy = fmaf(ww, y, swy);
        swz = fmaf(ww, z, swz);
    }

    #pragma unroll
    for (int off = WAVE / 2; off > 0; off >>= 1) {
        mnx = fminf(mnx, __shfl_down(mnx, off));
        mny = fminf(mny, __shfl_down(mny, off));
        mnz = fminf(mnz, __shfl_down(mnz, off));
        mxx = fmaxf(mxx, __shfl_down(mxx, off));
        mxy = fmaxf(mxy, __shfl_down(mxy, off));
        mxz = fmaxf(mxz, __shfl_down(mxz, off));
        sw  += __shfl_down(sw,  off);
        swx += __shfl_down(swx, off);
        swy += __shfl_down(swy, off);
        swz += __shfl_down(swz, off);
    }

    if (lane == 0) {
        float diam = fmaxf(mxx - mnx, fmaxf(mxy - mny, mxz - mnz));
        float wsafe = (sw == 0.f) ? 1.f : sw;
        seg[s] = make_float4(swx / wsafe, swy / wsafe, swz / wsafe,
                             1.f / (diam + 0.01f));
        diam_out[s] = diam;
    }
}

// Elementwise: out = (pos - center[idx]) * inv(diam[idx]+0.01). 4 points/thread,
// 3x float4 in / 3x float4 out.
__global__ void normalize_pts(const float* __restrict__ pos,
                              const void* __restrict__ idxp,
                              const int* __restrict__ flag,
                              const float4* __restrict__ seg,
                              float* __restrict__ out,
                              long long N) {
    long long t = (long long)blockIdx.x * blockDim.x + threadIdx.x;
    if (t >= (N >> 2)) return;
    const int is64 = *flag;

    const float4* __restrict__ pin = (const float4*)pos;
    float4 p0 = pin[t*3+0], p1 = pin[t*3+1], p2 = pin[t*3+2];
    const long long b = t << 2;

    float4 r0, r1, r2;
    {
        float4 sg = seg[load_idx(idxp, b + 0, is64)];
        r0.x = (p0.x - sg.x) * sg.w;
        r0.y = (p0.y - sg.y) * sg.w;
        r0.z = (p0.z - sg.z) * sg.w;
    }
    {
        float4 sg = seg[load_idx(idxp, b + 1, is64)];
        r0.w = (p0.w - sg.x) * sg.w;
        r1.x = (p1.x - sg.y) * sg.w;
        r1.y = (p1.y - sg.z) * sg.w;
    }
    {
        float4 sg = seg[load_idx(idxp, b + 2, is64)];
        r1.z = (p1.z - sg.x) * sg.w;
        r1.w = (p1.w - sg.y) * sg.w;
        r2.x = (p2.x - sg.z) * sg.w;
    }
    {
        float4 sg = seg[load_idx(idxp, b + 3, is64)];
        r2.y = (p2.y - sg.x) * sg.w;
        r2.z = (p2.z - sg.y) * sg.w;
        r2.w = (p2.w - sg.z) * sg.w;
    }
    float4* __restrict__ pout = (float4*)out;
    pout[t*3+0] = r0; pout[t*3+1] = r1; pout[t*3+2] = r2;
}

extern "C" void kernel_launch(void* const* d_in, const int* in_sizes, int n_in,
                              void* d_out, int out_size, void* d_ws, size_t ws_size,
                              hipStream_t stream) {
    const float* pos  = (const float*)d_in[0];
    const void*  idxp = d_in[1];
    const float* w    = (const float*)d_in[2];

    const long long N = (long long)in_sizes[0] / 3;     // 8388608
    const int S = out_size - in_sizes[0];               // 32768

    float* out = (float*)d_out;
    float* diam_out = out + (long long)in_sizes[0];     // tail of d_out

    // d_ws layout: [flag:4B pad to 256] [start:(S+1) ints, pad to 512-mult] [seg: S float4]
    int*    flag  = (int*)d_ws;
    int*    start = (int*)((char*)d_ws + 256);
    size_t  start_bytes = (((size_t)(S + 1) * 4 + 511) / 512) * 512;
    float4* seg   = (float4*)((char*)d_ws + 256 + start_bytes);

    detect_idx64<<<1, 64, 0, stream>>>((const unsigned int*)idxp, N, flag);

    find_bounds<<<(int)((N + 255) / 256), 256, 0, stream>>>(idxp, flag, start, N, S);

    seg_stats<<<(S + 3) / 4, 256, 0, stream>>>(pos, w, start, seg, diam_out, S);

    const long long nt = N >> 2;                        // 4 points per thread
    const int blocks = (int)((nt + 255) / 256);
    normalize_pts<<<blocks, 256, 0, stream>>>(pos, idxp, flag, seg, out, N);
}

// Round 3
// 75.437 us; speedup vs baseline: 2.9802x; 1.2213x over previous
//
#include <hip/hip_runtime.h>

#define WAVE 64
#define SPB 4   // segments per block (= waves per block)

// idx may be int32 (JAX default) or int64 (x64 enabled). Detection: odd 32-bit
// words in the upper half are high words of values < 2^31 under int64 layout
// (all zero); under int32 layout they are sorted values ~S/2 (nonzero).
__global__ void detect_idx64(const unsigned int* __restrict__ w32, long long N,
                             int* __restrict__ flag) {
    long long base = (N / 2) | 1LL;                 // odd position
    long long stride = ((N / 2) / 64) & ~1LL;       // even stride keeps parity
    if (stride < 2) stride = 2;
    long long p = base + (long long)threadIdx.x * stride;
    unsigned int v = (p < N) ? w32[p] : 0u;
    unsigned long long nz = __ballot(v != 0u);
    if (threadIdx.x == 0) *flag = (nz == 0ULL) ? 1 : 0;   // 1 -> int64
}

__device__ __forceinline__ int load_idx(const void* __restrict__ p,
                                        long long i, int is64) {
    return is64 ? (int)((const long long*)p)[i] : ((const int*)p)[i];
}

// Coalesced pass over idx: start[s] = lower_bound(idx, s). idx sorted, so
// wherever the value changes (prev < cur) write start[prev+1 .. cur] = i.
// Thread N-1 backfills the tail. Total writes = S+1.
__global__ void find_bounds(const void* __restrict__ idxp,
                            const int* __restrict__ flag,
                            int* __restrict__ start,
                            long long N, int S) {
    long long i = (long long)blockIdx.x * blockDim.x + threadIdx.x;
    if (i >= N) return;
    const int is64 = *flag;
    int cur  = load_idx(idxp, i, is64);
    int prev = (i == 0) ? -1 : load_idx(idxp, i - 1, is64);
    for (int s = prev + 1; s <= cur; ++s) start[s] = (int)i;
    if (i == N - 1)
        for (int s = cur + 1; s <= S; ++s) start[s] = (int)N;
}

// Fused: block owns SPB consecutive segments = contiguous point range.
// Pass 1: wave-per-segment min/max/weighted-sum reduction -> LDS (+ diam to
// global). Pass 2: whole block normalizes its point range; pos re-read hits
// L1/L2 (just loaded), segment id derived from LDS boundaries (no idx read).
__global__ __launch_bounds__(SPB * WAVE)
void seg_norm(const float* __restrict__ pos,
              const float* __restrict__ w,
              const int* __restrict__ start,
              float* __restrict__ out,
              float* __restrict__ diam_out,
              int S) {
    const int s0   = blockIdx.x * SPB;
    const int wid  = threadIdx.x >> 6;
    const int lane = threadIdx.x & 63;

    __shared__ int    sb[SPB + 1];
    __shared__ float4 sseg[SPB];

    if (threadIdx.x <= SPB) {
        int s = s0 + threadIdx.x;
        sb[threadIdx.x] = start[(s <= S) ? s : S];
    }
    __syncthreads();

    const int s = s0 + wid;
    if (s < S) {
        const int lo = sb[wid], hi = sb[wid + 1];

        float mnx = INFINITY,  mny = INFINITY,  mnz = INFINITY;
        float mxx = -INFINITY, mxy = -INFINITY, mxz = -INFINITY;
        float sw = 0.f, swx = 0.f, swy = 0.f, swz = 0.f;

        for (int i = lo + lane; i < hi; i += WAVE) {
            float x = pos[3LL*i], y = pos[3LL*i+1], z = pos[3LL*i+2];
            float ww = w[i];
            mnx = fminf(mnx, x); mxx = fmaxf(mxx, x);
            mny = fminf(mny, y); mxy = fmaxf(mxy, y);
            mnz = fminf(mnz, z); mxz = fmaxf(mxz, z);
            sw += ww;
            swx = fmaf(ww, x, swx);
            swy = fmaf(ww, y, swy);
            swz = fmaf(ww, z, swz);
        }

        #pragma unroll
        for (int off = WAVE / 2; off > 0; off >>= 1) {
            mnx = fminf(mnx, __shfl_down(mnx, off));
            mny = fminf(mny, __shfl_down(mny, off));
            mnz = fminf(mnz, __shfl_down(mnz, off));
            mxx = fmaxf(mxx, __shfl_down(mxx, off));
            mxy = fmaxf(mxy, __shfl_down(mxy, off));
            mxz = fmaxf(mxz, __shfl_down(mxz, off));
            sw  += __shfl_down(sw,  off);
            swx += __shfl_down(swx, off);
            swy += __shfl_down(swy, off);
            swz += __shfl_down(swz, off);
        }

        if (lane == 0) {
            float diam = fmaxf(mxx - mnx, fmaxf(mxy - mny, mxz - mnz));
            float wsafe = (sw == 0.f) ? 1.f : sw;
            sseg[wid] = make_float4(swx / wsafe, swy / wsafe, swz / wsafe,
                                    1.f / (diam + 0.01f));
            diam_out[s] = diam;
        }
    }
    __syncthreads();

    const int b0 = sb[0], b1 = sb[1], b2 = sb[2], b3 = sb[3], b4 = sb[SPB];
    for (int p = b0 + threadIdx.x; p < b4; p += SPB * WAVE) {
        int sl = (p >= b1) + (p >= b2) + (p >= b3);
        float4 c = sseg[sl];
        float x = pos[3LL*p], y = pos[3LL*p+1], z = pos[3LL*p+2];
        out[3LL*p]     = (x - c.x) * c.w;
        out[3LL*p + 1] = (y - c.y) * c.w;
        out[3LL*p + 2] = (z - c.z) * c.w;
    }
}

extern "C" void kernel_launch(void* const* d_in, const int* in_sizes, int n_in,
                              void* d_out, int out_size, void* d_ws, size_t ws_size,
                              hipStream_t stream) {
    const float* pos  = (const float*)d_in[0];
    const void*  idxp = d_in[1];
    const float* w    = (const float*)d_in[2];

    const long long N = (long long)in_sizes[0] / 3;     // 8388608
    const int S = out_size - in_sizes[0];               // 32768

    float* out = (float*)d_out;
    float* diam_out = out + (long long)in_sizes[0];     // tail of d_out

    // d_ws layout: [flag: 4B, pad to 256] [start: (S+1) ints]
    int* flag  = (int*)d_ws;
    int* start = (int*)((char*)d_ws + 256);

    detect_idx64<<<1, 64, 0, stream>>>((const unsigned int*)idxp, N, flag);

    find_bounds<<<(int)((N + 255) / 256), 256, 0, stream>>>(idxp, flag, start, N, S);

    seg_norm<<<(S + SPB - 1) / SPB, SPB * WAVE, 0, stream>>>(
        pos, w, start, out, diam_out, S);
}

// Round 4
// 67.829 us; speedup vs baseline: 3.3144x; 1.1122x over previous
//
#include <hip/hip_runtime.h>

#define WAVE 64
#define SPB 4   // segments (waves) per block

// idx may be int32 (JAX default) or int64 (x64 enabled). Detection: odd 32-bit
// words in the upper half are high words of values < 2^31 under int64 layout
// (all zero); under int32 layout they are sorted values ~S/2 (nonzero).
__global__ void detect_idx64(const unsigned int* __restrict__ w32, long long N,
                             int* __restrict__ flag) {
    long long base = (N / 2) | 1LL;
    long long stride = ((N / 2) / 64) & ~1LL;
    if (stride < 2) stride = 2;
    long long p = base + (long long)threadIdx.x * stride;
    unsigned int v = (p < N) ? w32[p] : 0u;
    unsigned long long nz = __ballot(v != 0u);
    if (threadIdx.x == 0) *flag = (nz == 0ULL) ? 1 : 0;   // 1 -> int64
}

__device__ __forceinline__ int load_idx(const void* __restrict__ p,
                                        long long i, int is64) {
    return is64 ? (int)((const long long*)p)[i] : ((const int*)p)[i];
}

// Coalesced pass over idx, 4 elements/thread: start[s] = lower_bound(idx, s).
__global__ void find_bounds(const void* __restrict__ idxp,
                            const int* __restrict__ flag,
                            int* __restrict__ start,
                            long long N, int S) {
    long long b = ((long long)blockIdx.x * blockDim.x + threadIdx.x) << 2;
    if (b >= N) return;
    const int is64 = *flag;
    int prev = (b == 0) ? -1 : load_idx(idxp, b - 1, is64);
    #pragma unroll
    for (int k = 0; k < 4; ++k) {
        long long i = b + k;
        if (i >= N) break;
        int cur = load_idx(idxp, i, is64);
        for (int s = prev + 1; s <= cur; ++s) start[s] = (int)i;
        prev = cur;
    }
    if (b + 4 >= N)
        for (int s = prev + 1; s <= S; ++s) start[s] = (int)N;
}

// One wave per segment, fully independent (no LDS, no barrier).
// Scan: lane owns 4 consecutive points = 3 aligned float4 pos loads + 1 float4
// w load, components at compile-time-known positions; points outside [lo,hi)
// masked. Butterfly __shfl_xor reduction -> all lanes hold stats. Normalize:
// same wave re-reads its range (L1-hot) and writes float4 (masked scalar at
// segment-boundary groups).
__global__ __launch_bounds__(SPB * WAVE)
void seg_norm(const float* __restrict__ pos,
              const float* __restrict__ w,
              const int* __restrict__ start,
              float* __restrict__ out,
              float* __restrict__ diam_out,
              int S) {
    const int s = blockIdx.x * SPB + (threadIdx.x >> 6);
    if (s >= S) return;
    const int lane = threadIdx.x & 63;

    const int lo = start[s], hi = start[s + 1];
    const int g0 = lo >> 2, g1 = (hi + 3) >> 2;       // 4-point groups

    const float4* __restrict__ pos4 = (const float4*)pos;
    const float4* __restrict__ w4   = (const float4*)w;

    float mnx = INFINITY,  mny = INFINITY,  mnz = INFINITY;
    float mxx = -INFINITY, mxy = -INFINITY, mxz = -INFINITY;
    float sw = 0.f, swx = 0.f, swy = 0.f, swz = 0.f;

    for (int g = g0 + lane; g < g1; g += WAVE) {
        float4 a = pos4[3LL * g], b = pos4[3LL * g + 1], c = pos4[3LL * g + 2];
        float4 ww = w4[g];
        const int p = g << 2;
        // p+0: (a.x,a.y,a.z) w.x | p+1: (a.w,b.x,b.y) w.y
        // p+2: (b.z,b.w,c.x) w.z | p+3: (c.y,c.z,c.w) w.w
        #define PROC(PI, X, Y, Z, WV)                                        \
        {                                                                    \
            bool in = ((PI) >= lo) & ((PI) < hi);                            \
            float xv = (X), yv = (Y), zv = (Z);                              \
            float wv = in ? (WV) : 0.f;                                      \
            mnx = fminf(mnx, in ? xv :  INFINITY);                           \
            mxx = fmaxf(mxx, in ? xv : -INFINITY);                           \
            mny = fminf(mny, in ? yv :  INFINITY);                           \
            mxy = fmaxf(mxy, in ? yv : -INFINITY);                           \
            mnz = fminf(mnz, in ? zv :  INFINITY);                           \
            mxz = fmaxf(mxz, in ? zv : -INFINITY);                           \
            sw += wv;                                                        \
            swx = fmaf(wv, xv, swx);                                         \
            swy = fmaf(wv, yv, swy);                                         \
            swz = fmaf(wv, zv, swz);                                         \
        }
        PROC(p + 0, a.x, a.y, a.z, ww.x)
        PROC(p + 1, a.w, b.x, b.y, ww.y)
        PROC(p + 2, b.z, b.w, c.x, ww.z)
        PROC(p + 3, c.y, c.z, c.w, ww.w)
        #undef PROC
    }

    #pragma unroll
    for (int off = 1; off < WAVE; off <<= 1) {
        mnx = fminf(mnx, __shfl_xor(mnx, off));
        mny = fminf(mny, __shfl_xor(mny, off));
        mnz = fminf(mnz, __shfl_xor(mnz, off));
        mxx = fmaxf(mxx, __shfl_xor(mxx, off));
        mxy = fmaxf(mxy, __shfl_xor(mxy, off));
        mxz = fmaxf(mxz, __shfl_xor(mxz, off));
        sw  += __shfl_xor(sw,  off);
        swx += __shfl_xor(swx, off);
        swy += __shfl_xor(swy, off);
        swz += __shfl_xor(swz, off);
    }

    const float diam = fmaxf(mxx - mnx, fmaxf(mxy - mny, mxz - mnz));
    const float wsafe = (sw == 0.f) ? 1.f : sw;
    const float cx = swx / wsafe, cy = swy / wsafe, cz = swz / wsafe;
    const float inv = 1.f / (diam + 0.01f);
    if (lane == 0) diam_out[s] = diam;

    float4* __restrict__ out4 = (float4*)out;
    for (int g = g0 + lane; g < g1; g += WAVE) {
        float4 a = pos4[3LL * g], b = pos4[3LL * g + 1], c = pos4[3LL * g + 2];
        float4 ra, rb, rc;
        ra.x = (a.x - cx) * inv; ra.y = (a.y - cy) * inv;
        ra.z = (a.z - cz) * inv; ra.w = (a.w - cx) * inv;
        rb.x = (b.x - cy) * inv; rb.y = (b.y - cz) * inv;
        rb.z = (b.z - cx) * inv; rb.w = (b.w - cy) * inv;
        rc.x = (c.x - cz) * inv; rc.y = (c.y - cx) * inv;
        rc.z = (c.z - cy) * inv; rc.w = (c.w - cz) * inv;
        const int p = g << 2;
        if (p >= lo && p + 4 <= hi) {
            out4[3LL * g] = ra; out4[3LL * g + 1] = rb; out4[3LL * g + 2] = rc;
        } else {
            const long long f = 12LL * g;
            if (p + 0 >= lo && p + 0 < hi) {
                out[f + 0] = ra.x; out[f + 1]  = ra.y; out[f + 2]  = ra.z;
            }
            if (p + 1 >= lo && p + 1 < hi) {
                out[f + 3] = ra.w; out[f + 4]  = rb.x; out[f + 5]  = rb.y;
            }
            if (p + 2 >= lo && p + 2 < hi) {
                out[f + 6] = rb.z; out[f + 7]  = rb.w; out[f + 8]  = rc.x;
            }
            if (p + 3 >= lo && p + 3 < hi) {
                out[f + 9] = rc.y; out[f + 10] = rc.z; out[f + 11] = rc.w;
            }
        }
    }
}

extern "C" void kernel_launch(void* const* d_in, const int* in_sizes, int n_in,
                              void* d_out, int out_size, void* d_ws, size_t ws_size,
                              hipStream_t stream) {
    const float* pos  = (const float*)d_in[0];
    const void*  idxp = d_in[1];
    const float* w    = (const float*)d_in[2];

    const long long N = (long long)in_sizes[0] / 3;     // 8388608
    const int S = out_size - in_sizes[0];               // 32768

    float* out = (float*)d_out;
    float* diam_out = out + (long long)in_sizes[0];     // tail of d_out

    int* flag  = (int*)d_ws;
    int* start = (int*)((char*)d_ws + 256);

    detect_idx64<<<1, 64, 0, stream>>>((const unsigned int*)idxp, N, flag);

    const long long nt4 = (N + 3) >> 2;
    find_bounds<<<(int)((nt4 + 255) / 256), 256, 0, stream>>>(idxp, flag, start, N, S);

    seg_norm<<<(S + SPB - 1) / SPB, SPB * WAVE, 0, stream>>>(
        pos, w, start, out, diam_out, S);
}

// Round 5
// 61.007 us; speedup vs baseline: 3.6851x; 1.1118x over previous
//
#include <hip/hip_runtime.h>

#define WAVE 64
#define SPB 4   // segments (waves) per block

// idx may be int32 (JAX default) or int64 (x64 enabled). Detection: odd 32-bit
// words in the upper half are high words of values < 2^31 under int64 layout
// (all zero); under int32 layout they are sorted values ~S/2 (nonzero).
__global__ void detect_idx64(const unsigned int* __restrict__ w32, long long N,
                             int* __restrict__ flag) {
    long long base = (N / 2) | 1LL;
    long long stride = ((N / 2) / 64) & ~1LL;
    if (stride < 2) stride = 2;
    long long p = base + (long long)threadIdx.x * stride;
    unsigned int v = (p < N) ? w32[p] : 0u;
    unsigned long long nz = __ballot(v != 0u);
    if (threadIdx.x == 0) *flag = (nz == 0ULL) ? 1 : 0;   // 1 -> int64
}

__device__ __forceinline__ int load_idx(const void* __restrict__ p,
                                        long long i, int is64) {
    return is64 ? (int)((const long long*)p)[i] : ((const int*)p)[i];
}

// Coalesced pass over idx, 4 elements/thread: start[s] = lower_bound(idx, s).
__global__ void find_bounds(const void* __restrict__ idxp,
                            const int* __restrict__ flag,
                            int* __restrict__ start,
                            long long N, int S) {
    long long b = ((long long)blockIdx.x * blockDim.x + threadIdx.x) << 2;
    if (b >= N) return;
    const int is64 = *flag;
    int prev = (b == 0) ? -1 : load_idx(idxp, b - 1, is64);
    #pragma unroll
    for (int k = 0; k < 4; ++k) {
        long long i = b + k;
        if (i >= N) break;
        int cur = load_idx(idxp, i, is64);
        for (int s = prev + 1; s <= cur; ++s) start[s] = (int)i;
        prev = cur;
    }
    if (b + 4 >= N)
        for (int s = prev + 1; s <= S; ++s) start[s] = (int)N;
}

// One wave per segment. Segment <= 512 points (<=2 lane-iterations) in the
// expected data; both iterations are peeled statically so all 8 float4 loads
// issue before any dependent use, and the SAME registers feed the normalize
// phase (no second memory round-trip). A never-taken dynamic tail loop keeps
// correctness for larger segments.
__global__ __launch_bounds__(SPB * WAVE)
void seg_norm(const float* __restrict__ pos,
              const float* __restrict__ w,
              const int* __restrict__ start,
              float* __restrict__ out,
              float* __restrict__ diam_out,
              int S) {
    const int s = blockIdx.x * SPB + (threadIdx.x >> 6);
    if (s >= S) return;
    const int lane = threadIdx.x & 63;

    const int lo = start[s], hi = start[s + 1];
    const int g0 = lo >> 2, g1 = (hi + 3) >> 2;       // 4-point groups

    const float4* __restrict__ pos4 = (const float4*)pos;
    const float4* __restrict__ w4   = (const float4*)w;

    const int ga = g0 + lane;          // iteration 0 group
    const int gb = ga + WAVE;          // iteration 1 group
    const bool va = ga < g1, vb = gb < g1;

    float4 a0 = {0,0,0,0}, a1 = {0,0,0,0}, a2 = {0,0,0,0}, aw = {0,0,0,0};
    float4 b0 = {0,0,0,0}, b1 = {0,0,0,0}, b2 = {0,0,0,0}, bw = {0,0,0,0};
    if (va) {
        a0 = pos4[3LL * ga]; a1 = pos4[3LL * ga + 1]; a2 = pos4[3LL * ga + 2];
        aw = w4[ga];
    }
    if (vb) {
        b0 = pos4[3LL * gb]; b1 = pos4[3LL * gb + 1]; b2 = pos4[3LL * gb + 2];
        bw = w4[gb];
    }

    float mnx = INFINITY,  mny = INFINITY,  mnz = INFINITY;
    float mxx = -INFINITY, mxy = -INFINITY, mxz = -INFINITY;
    float sw = 0.f, swx = 0.f, swy = 0.f, swz = 0.f;

    // p+0: (r0.x,r0.y,r0.z) w.x | p+1: (r0.w,r1.x,r1.y) w.y
    // p+2: (r1.z,r1.w,r2.x) w.z | p+3: (r2.y,r2.z,r2.w) w.w
    #define PROC(PI, X, Y, Z, WV)                                        \
    {                                                                    \
        bool in = ((PI) >= lo) & ((PI) < hi);                            \
        float xv = (X), yv = (Y), zv = (Z);                              \
        float wv = in ? (WV) : 0.f;                                      \
        mnx = fminf(mnx, in ? xv :  INFINITY);                           \
        mxx = fmaxf(mxx, in ? xv : -INFINITY);                           \
        mny = fminf(mny, in ? yv :  INFINITY);                           \
        mxy = fmaxf(mxy, in ? yv : -INFINITY);                           \
        mnz = fminf(mnz, in ? zv :  INFINITY);                           \
        mxz = fmaxf(mxz, in ? zv : -INFINITY);                           \
        sw += wv;                                                        \
        swx = fmaf(wv, xv, swx);                                         \
        swy = fmaf(wv, yv, swy);                                         \
        swz = fmaf(wv, zv, swz);                                         \
    }
    #define PROC_GROUP(G, R0, R1, R2, RW)                                \
    {                                                                    \
        const int p = (G) << 2;                                          \
        PROC(p + 0, R0.x, R0.y, R0.z, RW.x)                              \
        PROC(p + 1, R0.w, R1.x, R1.y, RW.y)                              \
        PROC(p + 2, R1.z, R1.w, R2.x, RW.z)                              \
        PROC(p + 3, R2.y, R2.z, R2.w, RW.w)                              \
    }

    PROC_GROUP(ga, a0, a1, a2, aw)
    PROC_GROUP(gb, b0, b1, b2, bw)

    // Pathological tail (segment > 512 points): never taken for this data.
    for (int g = g0 + 2 * WAVE + lane; g < g1; g += WAVE) {
        float4 c0 = pos4[3LL * g], c1 = pos4[3LL * g + 1], c2 = pos4[3LL * g + 2];
        float4 cw = w4[g];
        PROC_GROUP(g, c0, c1, c2, cw)
    }

    #pragma unroll
    for (int off = 1; off < WAVE; off <<= 1) {
        mnx = fminf(mnx, __shfl_xor(mnx, off));
        mny = fminf(mny, __shfl_xor(mny, off));
        mnz = fminf(mnz, __shfl_xor(mnz, off));
        mxx = fmaxf(mxx, __shfl_xor(mxx, off));
        mxy = fmaxf(mxy, __shfl_xor(mxy, off));
        mxz = fmaxf(mxz, __shfl_xor(mxz, off));
        sw  += __shfl_xor(sw,  off);
        swx += __shfl_xor(swx, off);
        swy += __shfl_xor(swy, off);
        swz += __shfl_xor(swz, off);
    }

    const float diam = fmaxf(mxx - mnx, fmaxf(mxy - mny, mxz - mnz));
    const float wsafe = (sw == 0.f) ? 1.f : sw;
    const float cx = swx / wsafe, cy = swy / wsafe, cz = swz / wsafe;
    const float inv = 1.f / (diam + 0.01f);
    if (lane == 0) diam_out[s] = diam;

    float4* __restrict__ out4 = (float4*)out;

    #define STORE_GROUP(G, R0, R1, R2)                                       \
    {                                                                        \
        const int p = (G) << 2;                                              \
        float4 ra, rb, rc;                                                   \
        ra.x = (R0.x - cx) * inv; ra.y = (R0.y - cy) * inv;                  \
        ra.z = (R0.z - cz) * inv; ra.w = (R0.w - cx) * inv;                  \
        rb.x = (R1.x - cy) * inv; rb.y = (R1.y - cz) * inv;                  \
        rb.z = (R1.z - cx) * inv; rb.w = (R1.w - cy) * inv;                  \
        rc.x = (R2.x - cz) * inv; rc.y = (R2.y - cx) * inv;                  \
        rc.z = (R2.z - cy) * inv; rc.w = (R2.w - cz) * inv;                  \
        if (p >= lo && p + 4 <= hi) {                                        \
            out4[3LL * (G)] = ra; out4[3LL * (G) + 1] = rb;                  \
            out4[3LL * (G) + 2] = rc;                                        \
        } else {                                                             \
            const long long f = 12LL * (G);                                  \
            if (p + 0 >= lo && p + 0 < hi) {                                 \
                out[f + 0] = ra.x; out[f + 1]  = ra.y; out[f + 2]  = ra.z;   \
            }                                                                \
            if (p + 1 >= lo && p + 1 < hi) {                                 \
                out[f + 3] = ra.w; out[f + 4]  = rb.x; out[f + 5]  = rb.y;   \
            }                                                                \
            if (p + 2 >= lo && p + 2 < hi) {                                 \
                out[f + 6] = rb.z; out[f + 7]  = rb.w; out[f + 8]  = rc.x;   \
            }                                                                \
            if (p + 3 >= lo && p + 3 < hi) {                                 \
                out[f + 9] = rc.y; out[f + 10] = rc.z; out[f + 11] = rc.w;   \
            }                                                                \
        }                                                                    \
    }

    STORE_GROUP(ga, a0, a1, a2)   // covers all in-range points; inactive
    STORE_GROUP(gb, b0, b1, b2)   // lanes fail every per-point range test

    // Tail normalize (reload path; never taken for this data).
    for (int g = g0 + 2 * WAVE + lane; g < g1; g += WAVE) {
        float4 c0 = pos4[3LL * g], c1 = pos4[3LL * g + 1], c2 = pos4[3LL * g + 2];
        STORE_GROUP(g, c0, c1, c2)
    }

    #undef STORE_GROUP
    #undef PROC_GROUP
    #undef PROC
}

extern "C" void kernel_launch(void* const* d_in, const int* in_sizes, int n_in,
                              void* d_out, int out_size, void* d_ws, size_t ws_size,
                              hipStream_t stream) {
    const float* pos  = (const float*)d_in[0];
    const void*  idxp = d_in[1];
    const float* w    = (const float*)d_in[2];

    const long long N = (long long)in_sizes[0] / 3;     // 8388608
    const int S = out_size - in_sizes[0];               // 32768

    float* out = (float*)d_out;
    float* diam_out = out + (long long)in_sizes[0];     // tail of d_out

    int* flag  = (int*)d_ws;
    int* start = (int*)((char*)d_ws + 256);

    detect_idx64<<<1, 64, 0, stream>>>((const unsigned int*)idxp, N, flag);

    const long long nt4 = (N + 3) >> 2;
    find_bounds<<<(int)((nt4 + 255) / 256), 256, 0, stream>>>(idxp, flag, start, N, S);

    seg_norm<<<(S + SPB - 1) / SPB, SPB * WAVE, 0, stream>>>(
        pos, w, start, out, diam_out, S);
}